// Round 2
// baseline (338.964 us; speedup 1.0000x reference)
//
#include <hip/hip_runtime.h>
#include <math.h>

#define D_DIM   1024
#define N_MODES 16
#define B_DIM   8
#define L_DIM   4096
#define CHUNK   64          // per-lane time chunk: 64 lanes * 64 = L
#define SCALE_F 0.25f       // sqrt(1/N)
#define WPB     4           // waves per 256-thread block, one row per wave

// Phase 2: recurrence from carry state + projection + residual, in 16-elem
// groups with burst loads/stores so 64B lines are completed quickly.
template<bool USE_CI>
__device__ __forceinline__ void phase2_run(const float* __restrict__ xrow,
                                           float* __restrict__ yrow,
                                           const float (&qr)[N_MODES],
                                           const float (&qi)[N_MODES],
                                           float (&hr)[N_MODES],
                                           float (&hi)[N_MODES],
                                           const float (&cr)[N_MODES],
                                           const float (&ci)[N_MODES],
                                           float om)
{
#pragma unroll
    for (int g = 0; g < CHUNK; g += 16) {
        float xs[16];
#pragma unroll
        for (int v = 0; v < 4; ++v) {
            const float4 t = *reinterpret_cast<const float4*>(xrow + g + 4 * v);
            xs[4 * v + 0] = t.x; xs[4 * v + 1] = t.y;
            xs[4 * v + 2] = t.z; xs[4 * v + 3] = t.w;
        }
        float ys[16];
#pragma unroll
        for (int e = 0; e < 16; ++e) {
            const float xe = xs[e];
            float acc = om * xe;
#pragma unroll
            for (int n = 0; n < N_MODES; ++n) {
                const float t  = fmaf(qr[n], hr[n], xe);
                const float nr = fmaf(-qi[n], hi[n], t);
                const float ni = fmaf(qr[n], hi[n], qi[n] * hr[n]);
                hr[n] = nr; hi[n] = ni;
                acc = fmaf(cr[n], nr, acc);
                if (USE_CI) acc = fmaf(-ci[n], ni, acc);
            }
            ys[e] = acc;
        }
        // burst store: 4 consecutive float4 -> one complete 64B line per lane
#pragma unroll
        for (int v = 0; v < 4; ++v) {
            float4 t;
            t.x = ys[4 * v + 0]; t.y = ys[4 * v + 1];
            t.z = ys[4 * v + 2]; t.w = ys[4 * v + 3];
            *reinterpret_cast<float4*>(yrow + g + 4 * v) = t;
        }
    }
}

__global__ __launch_bounds__(256, 4)
void ema_scan_kernel(const float* __restrict__ x,
                     const float* __restrict__ p_logit,
                     const float* __restrict__ lqr,
                     const float* __restrict__ lqi,
                     const float* __restrict__ gr,
                     const float* __restrict__ gi,
                     const float* __restrict__ omega,
                     float* __restrict__ out)
{
    const int wave = threadIdx.x >> 6;
    const int lane = threadIdx.x & 63;
    const int row  = blockIdx.x * WPB + wave;     // b * D + d
    const int d    = row & (D_DIM - 1);

    // ---- per-mode pole q = exp(log_q) (wave-redundant setup, cheap) ----
    float qr[N_MODES], qi[N_MODES];
#pragma unroll
    for (int n = 0; n < N_MODES; ++n) {
        const int idx = d * N_MODES + n;
        const float er = __expf(lqr[idx]);
        float s, c;
        __sincosf(lqi[idx], &s, &c);
        qr[n] = er * c;
        qi[n] = er * s;
    }

    const float* xrow = x   + (size_t)row * L_DIM + (size_t)lane * CHUNK;
    float*       yrow = out + (size_t)row * L_DIM + (size_t)lane * CHUNK;

    float hr[N_MODES], hi[N_MODES];
#pragma unroll
    for (int n = 0; n < N_MODES; ++n) { hr[n] = 0.0f; hi[n] = 0.0f; }

    // ---- phase 1: local recurrence from zero state over this lane's chunk ----
#pragma unroll
    for (int g = 0; g < CHUNK; g += 16) {
        float xs[16];
#pragma unroll
        for (int v = 0; v < 4; ++v) {
            const float4 t = *reinterpret_cast<const float4*>(xrow + g + 4 * v);
            xs[4 * v + 0] = t.x; xs[4 * v + 1] = t.y;
            xs[4 * v + 2] = t.z; xs[4 * v + 3] = t.w;
        }
#pragma unroll
        for (int e = 0; e < 16; ++e) {
            const float xe = xs[e];
#pragma unroll
            for (int n = 0; n < N_MODES; ++n) {
                const float t  = fmaf(qr[n], hr[n], xe);
                const float nr = fmaf(-qi[n], hi[n], t);
                const float ni = fmaf(qr[n], hi[n], qi[n] * hr[n]);
                hr[n] = nr; hi[n] = ni;
            }
        }
    }

    // ---- ratio A = q^CHUNK via 6 squarings ----
    float rr[N_MODES], ri[N_MODES];
#pragma unroll
    for (int n = 0; n < N_MODES; ++n) { rr[n] = qr[n]; ri[n] = qi[n]; }
#pragma unroll
    for (int k = 0; k < 6; ++k) {
#pragma unroll
        for (int n = 0; n < N_MODES; ++n) {
            const float a = rr[n], b = ri[n];
            rr[n] = fmaf(a, a, -b * b);
            ri[n] = 2.0f * a * b;
        }
    }

    // ---- inclusive Hillis-Steele scan across 64 lanes: h_l += A^off * h_{l-off} ----
#pragma unroll
    for (int off = 1; off < 64; off <<= 1) {
#pragma unroll
        for (int n = 0; n < N_MODES; ++n) {
            const float pr = __shfl_up(hr[n], off);
            const float pi = __shfl_up(hi[n], off);
            if (lane >= off) {
                const float t0 = fmaf(rr[n], pr, fmaf(-ri[n], pi, hr[n]));
                const float t1 = fmaf(rr[n], pi, fmaf( ri[n], pr, hi[n]));
                hr[n] = t0; hi[n] = t1;
            }
        }
        if (off < 32) {
#pragma unroll
            for (int n = 0; n < N_MODES; ++n) {
                const float a = rr[n], b = ri[n];
                rr[n] = fmaf(a, a, -b * b);
                ri[n] = 2.0f * a * b;
            }
        }
    }

    // ---- exclusive: carry-in = inclusive value of lane-1 (0 for lane 0) ----
#pragma unroll
    for (int n = 0; n < N_MODES; ++n) {
        const float pr = __shfl_up(hr[n], 1);
        const float pi = __shfl_up(hi[n], 1);
        hr[n] = (lane == 0) ? 0.0f : pr;
        hi[n] = (lane == 0) ? 0.0f : pi;
    }

    // ---- projection coefficients (loaded late to shorten live range) ----
    float cr[N_MODES], ci[N_MODES];
    bool ci_zero = true;
#pragma unroll
    for (int n = 0; n < N_MODES; ++n) {
        const int idx = d * N_MODES + n;
        const float p = 1.0f / (1.0f + __expf(-p_logit[idx]));
        const float g = SCALE_F * p;
        cr[n] = gr[idx] * g;
        ci[n] = gi[idx] * g;
        ci_zero = ci_zero && (ci[n] == 0.0f);
    }
    const float om = omega[d];

    // d is wave-uniform -> branch is wave-uniform; ci==0 on the actual data
    if (ci_zero)
        phase2_run<false>(xrow, yrow, qr, qi, hr, hi, cr, ci, om);
    else
        phase2_run<true >(xrow, yrow, qr, qi, hr, hi, cr, ci, om);
}

extern "C" void kernel_launch(void* const* d_in, const int* in_sizes, int n_in,
                              void* d_out, int out_size, void* d_ws, size_t ws_size,
                              hipStream_t stream)
{
    const float* x   = (const float*)d_in[0];
    const float* pl  = (const float*)d_in[1];
    const float* lqr = (const float*)d_in[2];
    const float* lqi = (const float*)d_in[3];
    const float* gr  = (const float*)d_in[4];
    const float* gi  = (const float*)d_in[5];
    const float* om  = (const float*)d_in[6];
    float* out = (float*)d_out;

    dim3 grid((B_DIM * D_DIM) / WPB);   // one 64-lane wave per (b, d) row
    dim3 block(64 * WPB);
    ema_scan_kernel<<<grid, block, 0, stream>>>(x, pl, lqr, lqi, gr, gi, om, out);
}

// Round 3
// 152.156 us; speedup vs baseline: 2.2277x; 2.2277x over previous
//
#include <hip/hip_runtime.h>
#include <math.h>

#define D_DIM   1024
#define N_MODES 16
#define NPAIR   8           // modes packed 2-per-VGPR-pair for v_pk_fma_f32
#define B_DIM   8
#define L_DIM   4096
#define CHUNK   64          // per-lane time chunk: 64 lanes * 64 = L
#define SCALE_F 0.25f       // sqrt(1/N)
#define WPB     4           // waves per 256-thread block, one row per wave

typedef float v2f __attribute__((ext_vector_type(2)));

__device__ __forceinline__ v2f fma2(v2f a, v2f b, v2f c) {
#if __has_builtin(__builtin_elementwise_fma)
    return __builtin_elementwise_fma(a, b, c);   // -> v_pk_fma_f32
#else
    v2f r; r.x = fmaf(a.x, b.x, c.x); r.y = fmaf(a.y, b.y, c.y); return r;
#endif
}

// Phase 2: recurrence from carry state + projection + residual.
// GROUP=16 bursts 4 float4 stores back-to-back so each 64B line completes
// immediately (fixes the 1.74x write amplification seen in round 1).
template<bool USE_CI, int GROUP>
__device__ __forceinline__ void phase2_run(const float* __restrict__ xrow,
                                           float* __restrict__ yrow,
                                           const v2f (&qr)[NPAIR],
                                           const v2f (&qi)[NPAIR],
                                           v2f (&hr)[NPAIR],
                                           v2f (&hi)[NPAIR],
                                           const v2f (&cr)[NPAIR],
                                           const v2f (&ci)[NPAIR],
                                           float om)
{
#pragma unroll
    for (int g = 0; g < CHUNK; g += GROUP) {
        float xs[GROUP];
#pragma unroll
        for (int v = 0; v < GROUP / 4; ++v) {
            const float4 t = *reinterpret_cast<const float4*>(xrow + g + 4 * v);
            xs[4 * v + 0] = t.x; xs[4 * v + 1] = t.y;
            xs[4 * v + 2] = t.z; xs[4 * v + 3] = t.w;
        }
#pragma unroll
        for (int e = 0; e < GROUP; ++e) {
            const float xe = xs[e];
            v2f x2; x2.x = xe; x2.y = xe;
            v2f acc; acc.x = 0.0f; acc.y = 0.0f;
#pragma unroll
            for (int p = 0; p < NPAIR; ++p) {
                const v2f t  = fma2(qr[p], hr[p], x2);
                const v2f nr = fma2(-qi[p], hi[p], t);
                const v2f ni = fma2(qr[p], hi[p], qi[p] * hr[p]);
                hr[p] = nr; hi[p] = ni;
                acc = fma2(cr[p], nr, acc);
                if (USE_CI) acc = fma2(-ci[p], ni, acc);
            }
            xs[e] = fmaf(om, xe, acc.x + acc.y);   // in-place: saves 16 VGPRs
        }
#pragma unroll
        for (int v = 0; v < GROUP / 4; ++v) {
            float4 t;
            t.x = xs[4 * v + 0]; t.y = xs[4 * v + 1];
            t.z = xs[4 * v + 2]; t.w = xs[4 * v + 3];
            *reinterpret_cast<float4*>(yrow + g + 4 * v) = t;
        }
    }
}

__global__ __launch_bounds__(256)   // NO min-waves clamp: round 2's (256,4) forced 64 VGPR + spills
void ema_scan_kernel(const float* __restrict__ x,
                     const float* __restrict__ p_logit,
                     const float* __restrict__ lqr,
                     const float* __restrict__ lqi,
                     const float* __restrict__ gr,
                     const float* __restrict__ gi,
                     const float* __restrict__ omega,
                     float* __restrict__ out)
{
    const int wave = threadIdx.x >> 6;
    const int lane = threadIdx.x & 63;
    const int row  = blockIdx.x * WPB + wave;     // b * D + d
    const int d    = row & (D_DIM - 1);

    // ---- per-mode pole q = exp(log_q), packed 2 modes per v2f ----
    v2f qr[NPAIR], qi[NPAIR];
#pragma unroll
    for (int n = 0; n < N_MODES; ++n) {
        const int idx = d * N_MODES + n;
        const float er = __expf(lqr[idx]);
        float s, c;
        __sincosf(lqi[idx], &s, &c);
        qr[n >> 1][n & 1] = er * c;
        qi[n >> 1][n & 1] = er * s;
    }

    const float* xrow = x   + (size_t)row * L_DIM + (size_t)lane * CHUNK;
    float*       yrow = out + (size_t)row * L_DIM + (size_t)lane * CHUNK;

    v2f hr[NPAIR], hi[NPAIR];
#pragma unroll
    for (int p = 0; p < NPAIR; ++p) { hr[p] = (v2f)(0.0f); hi[p] = (v2f)(0.0f); }

    // ---- phase 1: local recurrence from zero state over this lane's chunk ----
#pragma unroll
    for (int g = 0; g < CHUNK; g += 16) {
        float xs[16];
#pragma unroll
        for (int v = 0; v < 4; ++v) {
            const float4 t = *reinterpret_cast<const float4*>(xrow + g + 4 * v);
            xs[4 * v + 0] = t.x; xs[4 * v + 1] = t.y;
            xs[4 * v + 2] = t.z; xs[4 * v + 3] = t.w;
        }
#pragma unroll
        for (int e = 0; e < 16; ++e) {
            v2f x2; x2.x = xs[e]; x2.y = xs[e];
#pragma unroll
            for (int p = 0; p < NPAIR; ++p) {
                const v2f t  = fma2(qr[p], hr[p], x2);
                const v2f nr = fma2(-qi[p], hi[p], t);
                const v2f ni = fma2(qr[p], hi[p], qi[p] * hr[p]);
                hr[p] = nr; hi[p] = ni;
            }
        }
    }

    // ---- ratio A = q^CHUNK via 6 squarings (packed) ----
    v2f rr[NPAIR], ri[NPAIR];
#pragma unroll
    for (int p = 0; p < NPAIR; ++p) { rr[p] = qr[p]; ri[p] = qi[p]; }
#pragma unroll
    for (int k = 0; k < 6; ++k) {
#pragma unroll
        for (int p = 0; p < NPAIR; ++p) {
            const v2f a = rr[p], b = ri[p];
            rr[p] = fma2(a, a, -(b * b));
            ri[p] = (v2f)(2.0f) * a * b;
        }
    }

    // ---- inclusive Hillis-Steele scan across 64 lanes ----
#pragma unroll
    for (int off = 1; off < 64; off <<= 1) {
#pragma unroll
        for (int p = 0; p < NPAIR; ++p) {
            v2f pr, pi;
            pr.x = __shfl_up(hr[p].x, off); pr.y = __shfl_up(hr[p].y, off);
            pi.x = __shfl_up(hi[p].x, off); pi.y = __shfl_up(hi[p].y, off);
            if (lane >= off) {
                const v2f t0 = fma2(rr[p], pr, fma2(-ri[p], pi, hr[p]));
                const v2f t1 = fma2(rr[p], pi, fma2( ri[p], pr, hi[p]));
                hr[p] = t0; hi[p] = t1;
            }
        }
        if (off < 32) {
#pragma unroll
            for (int p = 0; p < NPAIR; ++p) {
                const v2f a = rr[p], b = ri[p];
                rr[p] = fma2(a, a, -(b * b));
                ri[p] = (v2f)(2.0f) * a * b;
            }
        }
    }

    // ---- exclusive: carry-in = inclusive value of lane-1 (0 for lane 0) ----
#pragma unroll
    for (int p = 0; p < NPAIR; ++p) {
        v2f pr, pi;
        pr.x = __shfl_up(hr[p].x, 1); pr.y = __shfl_up(hr[p].y, 1);
        pi.x = __shfl_up(hi[p].x, 1); pi.y = __shfl_up(hi[p].y, 1);
        hr[p] = (lane == 0) ? (v2f)(0.0f) : pr;
        hi[p] = (lane == 0) ? (v2f)(0.0f) : pi;
    }

    // ---- projection coefficients ----
    v2f cr[NPAIR], ci[NPAIR];
    bool ci_zero = true;
#pragma unroll
    for (int n = 0; n < N_MODES; ++n) {
        const int idx = d * N_MODES + n;
        const float p = 1.0f / (1.0f + __expf(-p_logit[idx]));
        const float g = SCALE_F * p;
        cr[n >> 1][n & 1] = gr[idx] * g;
        ci[n >> 1][n & 1] = gi[idx] * g;
        ci_zero = ci_zero && (gi[idx] == 0.0f);
    }
    const float om = omega[d];

    // d is wave-uniform -> branch is wave-uniform; ci==0 on the actual data.
    // true-path uses GROUP=8 so its extra ci registers don't set peak pressure.
    if (ci_zero)
        phase2_run<false, 16>(xrow, yrow, qr, qi, hr, hi, cr, ci, om);
    else
        phase2_run<true, 8>(xrow, yrow, qr, qi, hr, hi, cr, ci, om);
}

extern "C" void kernel_launch(void* const* d_in, const int* in_sizes, int n_in,
                              void* d_out, int out_size, void* d_ws, size_t ws_size,
                              hipStream_t stream)
{
    const float* x   = (const float*)d_in[0];
    const float* pl  = (const float*)d_in[1];
    const float* lqr = (const float*)d_in[2];
    const float* lqi = (const float*)d_in[3];
    const float* gr  = (const float*)d_in[4];
    const float* gi  = (const float*)d_in[5];
    const float* om  = (const float*)d_in[6];
    float* out = (float*)d_out;

    dim3 grid((B_DIM * D_DIM) / WPB);   // one 64-lane wave per (b, d) row
    dim3 block(64 * WPB);
    ema_scan_kernel<<<grid, block, 0, stream>>>(x, pl, lqr, lqi, gr, gi, om, out);
}

// Round 4
// 140.588 us; speedup vs baseline: 2.4110x; 1.0823x over previous
//
#include <hip/hip_runtime.h>
#include <math.h>

#define D_DIM   1024
#define N_MODES 16
#define NPAIR   8           // modes packed 2-per-VGPR-pair for v_pk_fma_f32
#define B_DIM   8
#define L_DIM   4096
#define CHUNK   64          // per-lane time chunk: 64 lanes * 64 = L
#define SCALE_F 0.25f       // sqrt(1/N)
#define WPB     4           // waves per 256-thread block, one row per wave
#define GROUP   16          // elems per rolled-loop iteration

typedef float v2f __attribute__((ext_vector_type(2)));

__device__ __forceinline__ v2f fma2(v2f a, v2f b, v2f c) {
#if __has_builtin(__builtin_elementwise_fma)
    return __builtin_elementwise_fma(a, b, c);   // -> v_pk_fma_f32
#else
    v2f r; r.x = fmaf(a.x, b.x, c.x); r.y = fmaf(a.y, b.y, c.y); return r;
#endif
}

// Phase 2: recurrence from carry state + projection + residual.
// Rolled outer loop (4 iters) keeps the hot body ~5KB so it stays in L1I
// (round 3's full unroll = ~48KB straight-line code -> I$ thrash, VALUBusy 31%).
// Register double-buffer prefetch hides the load latency the rolled loop exposes.
// Burst stores at group end keep 64B lines completing back-to-back.
template<bool USE_CI>
__device__ __forceinline__ void phase2_run(const float* __restrict__ xrow,
                                           float* __restrict__ yrow,
                                           const v2f (&qr)[NPAIR],
                                           const v2f (&qi)[NPAIR],
                                           v2f (&hr)[NPAIR],
                                           v2f (&hi)[NPAIR],
                                           const v2f (&cr)[NPAIR],
                                           const v2f (&ci)[NPAIR],
                                           float om)
{
    float4 buf[4];
#pragma unroll
    for (int v = 0; v < 4; ++v)
        buf[v] = *reinterpret_cast<const float4*>(xrow + 4 * v);

#pragma unroll 1
    for (int g = 0; g < 4; ++g) {
        const int gn = (g < 3) ? g + 1 : 3;      // clamped prefetch (uniform)
        float4 nxt[4];
#pragma unroll
        for (int v = 0; v < 4; ++v)
            nxt[v] = *reinterpret_cast<const float4*>(xrow + gn * GROUP + 4 * v);

        float* bf = reinterpret_cast<float*>(buf);
#pragma unroll
        for (int e = 0; e < GROUP; ++e) {        // e is compile-time: regs, no scratch
            const float xe = bf[e];
            v2f x2; x2.x = xe; x2.y = xe;
            v2f acc; acc.x = 0.0f; acc.y = 0.0f;
#pragma unroll
            for (int p = 0; p < NPAIR; ++p) {
                const v2f t  = fma2(qr[p], hr[p], x2);
                const v2f nr = fma2(-qi[p], hi[p], t);
                const v2f ni = fma2(qr[p], hi[p], qi[p] * hr[p]);
                hr[p] = nr; hi[p] = ni;
                acc = fma2(cr[p], nr, acc);
                if (USE_CI) acc = fma2(-ci[p], ni, acc);
            }
            bf[e] = fmaf(om, xe, acc.x + acc.y); // in-place: slot consumed above
        }
#pragma unroll
        for (int v = 0; v < 4; ++v)              // burst: 64B line completes at once
            *reinterpret_cast<float4*>(yrow + g * GROUP + 4 * v) = buf[v];
#pragma unroll
        for (int v = 0; v < 4; ++v) buf[v] = nxt[v];
    }
}

__global__ __launch_bounds__(256)   // no min-waves clamp: (256,4) forced 64 VGPR + spills in round 2
void ema_scan_kernel(const float* __restrict__ x,
                     const float* __restrict__ p_logit,
                     const float* __restrict__ lqr,
                     const float* __restrict__ lqi,
                     const float* __restrict__ gr,
                     const float* __restrict__ gi,
                     const float* __restrict__ omega,
                     float* __restrict__ out)
{
    const int wave = threadIdx.x >> 6;
    const int lane = threadIdx.x & 63;
    const int row  = blockIdx.x * WPB + wave;     // b * D + d
    const int d    = row & (D_DIM - 1);

    // ---- per-mode pole q = exp(log_q), packed 2 modes per v2f ----
    v2f qr[NPAIR], qi[NPAIR];
#pragma unroll
    for (int n = 0; n < N_MODES; ++n) {
        const int idx = d * N_MODES + n;
        const float er = __expf(lqr[idx]);
        float s, c;
        __sincosf(lqi[idx], &s, &c);
        qr[n >> 1][n & 1] = er * c;
        qi[n >> 1][n & 1] = er * s;
    }

    const float* xrow = x   + (size_t)row * L_DIM + (size_t)lane * CHUNK;
    float*       yrow = out + (size_t)row * L_DIM + (size_t)lane * CHUNK;

    v2f hr[NPAIR], hi[NPAIR];
#pragma unroll
    for (int p = 0; p < NPAIR; ++p) { hr[p] = (v2f)(0.0f); hi[p] = (v2f)(0.0f); }

    // ---- phase 1: local recurrence from zero state (rolled + prefetch) ----
    {
        float4 buf[4];
#pragma unroll
        for (int v = 0; v < 4; ++v)
            buf[v] = *reinterpret_cast<const float4*>(xrow + 4 * v);

#pragma unroll 1
        for (int g = 0; g < 4; ++g) {
            const int gn = (g < 3) ? g + 1 : 3;
            float4 nxt[4];
#pragma unroll
            for (int v = 0; v < 4; ++v)
                nxt[v] = *reinterpret_cast<const float4*>(xrow + gn * GROUP + 4 * v);

            const float* bf = reinterpret_cast<const float*>(buf);
#pragma unroll
            for (int e = 0; e < GROUP; ++e) {
                v2f x2; x2.x = bf[e]; x2.y = bf[e];
#pragma unroll
                for (int p = 0; p < NPAIR; ++p) {
                    const v2f t  = fma2(qr[p], hr[p], x2);
                    const v2f nr = fma2(-qi[p], hi[p], t);
                    const v2f ni = fma2(qr[p], hi[p], qi[p] * hr[p]);
                    hr[p] = nr; hi[p] = ni;
                }
            }
#pragma unroll
            for (int v = 0; v < 4; ++v) buf[v] = nxt[v];
        }
    }

    // ---- ratio A = q^CHUNK via 6 squarings (packed) ----
    v2f rr[NPAIR], ri[NPAIR];
#pragma unroll
    for (int p = 0; p < NPAIR; ++p) { rr[p] = qr[p]; ri[p] = qi[p]; }
#pragma unroll
    for (int k = 0; k < 6; ++k) {
#pragma unroll
        for (int p = 0; p < NPAIR; ++p) {
            const v2f a = rr[p], b = ri[p];
            rr[p] = fma2(a, a, -(b * b));
            ri[p] = (v2f)(2.0f) * a * b;
        }
    }

    // ---- inclusive Hillis-Steele scan across 64 lanes ----
#pragma unroll
    for (int off = 1; off < 64; off <<= 1) {
#pragma unroll
        for (int p = 0; p < NPAIR; ++p) {
            v2f pr, pi;
            pr.x = __shfl_up(hr[p].x, off); pr.y = __shfl_up(hr[p].y, off);
            pi.x = __shfl_up(hi[p].x, off); pi.y = __shfl_up(hi[p].y, off);
            if (lane >= off) {
                const v2f t0 = fma2(rr[p], pr, fma2(-ri[p], pi, hr[p]));
                const v2f t1 = fma2(rr[p], pi, fma2( ri[p], pr, hi[p]));
                hr[p] = t0; hi[p] = t1;
            }
        }
        if (off < 32) {
#pragma unroll
            for (int p = 0; p < NPAIR; ++p) {
                const v2f a = rr[p], b = ri[p];
                rr[p] = fma2(a, a, -(b * b));
                ri[p] = (v2f)(2.0f) * a * b;
            }
        }
    }

    // ---- exclusive: carry-in = inclusive value of lane-1 (0 for lane 0) ----
#pragma unroll
    for (int p = 0; p < NPAIR; ++p) {
        v2f pr, pi;
        pr.x = __shfl_up(hr[p].x, 1); pr.y = __shfl_up(hr[p].y, 1);
        pi.x = __shfl_up(hi[p].x, 1); pi.y = __shfl_up(hi[p].y, 1);
        hr[p] = (lane == 0) ? (v2f)(0.0f) : pr;
        hi[p] = (lane == 0) ? (v2f)(0.0f) : pi;
    }

    // ---- projection coefficients (loaded after scan: shorter live range) ----
    v2f cr[NPAIR], ci[NPAIR];
    bool ci_zero = true;
#pragma unroll
    for (int n = 0; n < N_MODES; ++n) {
        const int idx = d * N_MODES + n;
        const float p = 1.0f / (1.0f + __expf(-p_logit[idx]));
        const float g = SCALE_F * p;
        cr[n >> 1][n & 1] = gr[idx] * g;
        ci[n >> 1][n & 1] = gi[idx] * g;
        ci_zero = ci_zero && (gi[idx] == 0.0f);
    }
    const float om = omega[d];

    // d is wave-uniform -> branch is wave-uniform; ci==0 on the actual data
    if (ci_zero)
        phase2_run<false>(xrow, yrow, qr, qi, hr, hi, cr, ci, om);
    else
        phase2_run<true >(xrow, yrow, qr, qi, hr, hi, cr, ci, om);
}

extern "C" void kernel_launch(void* const* d_in, const int* in_sizes, int n_in,
                              void* d_out, int out_size, void* d_ws, size_t ws_size,
                              hipStream_t stream)
{
    const float* x   = (const float*)d_in[0];
    const float* pl  = (const float*)d_in[1];
    const float* lqr = (const float*)d_in[2];
    const float* lqi = (const float*)d_in[3];
    const float* gr  = (const float*)d_in[4];
    const float* gi  = (const float*)d_in[5];
    const float* om  = (const float*)d_in[6];
    float* out = (float*)d_out;

    dim3 grid((B_DIM * D_DIM) / WPB);   // one 64-lane wave per (b, d) row
    dim3 block(64 * WPB);
    ema_scan_kernel<<<grid, block, 0, stream>>>(x, pl, lqr, lqi, gr, gi, om, out);
}